// Round 7
// baseline (294.496 us; speedup 1.0000x reference)
//
#include <hip/hip_runtime.h>
#include <cstdint>
#include <cstddef>

// R12: k1 folded into k2. Each block computes its OWN h0 + gi slice via a
// pre-GEMM (K=256, A=zx16, B=wcat16 slice): gi accumulators land in registers
// in exactly the epilogue's fragment layout and stay there for all 12 steps
// (R11 re-loaded 48 scalars/thread/step from L2). h0 flows through the
// validated XCD-local exchange (g_h[0]). xs-prologue moved AFTER the GEMM to
// hide g_P latency under MFMA. Step-loop GEMM/epilogue/publish/barrier are
// byte-identical to validated R11. 2 launches: k0 (casts) + k2.

typedef __attribute__((ext_vector_type(8))) _Float16 f16x8;
typedef __attribute__((ext_vector_type(4))) float floatx4;

__device__ unsigned g_cnt[8 * 64];     // per-XCD registration tickets (padded)
__device__ unsigned g_gbar[16 * 64];   // per-group barrier counters (padded)

// Static exchange buffers (outside workspace -> never poisoned; step-indexed).
// g_h[0] = h0, g_h[t+1] = h after step t.
__device__ __align__(256) _Float16 g_h[12][4096 * 512 + 2048];
__device__ __align__(256) float    g_P[12][4096 * 2 * 16];

__device__ __forceinline__ float sigm_f(float v) { return 1.0f / (1.0f + __expf(-v)); }
__device__ __forceinline__ float tanh_f(float v) { return 2.0f / (1.0f + __expf(-2.0f * v)) - 1.0f; }

__device__ __forceinline__ void async16(void* lds, const void* g) {
    __builtin_amdgcn_global_load_lds(
        (const __attribute__((address_space(1))) void*)g,
        (__attribute__((address_space(3))) void*)lds, 16, 0, 0);
}

// Per-group barrier: EXACTLY 16 co-resident same-XCD blocks (validated R11).
__device__ __forceinline__ void group_barrier16(unsigned gidx) {
    asm volatile("s_waitcnt vmcnt(0)" ::: "memory");
    __syncthreads();
    if (threadIdx.x == 0) {
        unsigned* ctr = &g_gbar[gidx * 64];
        unsigned t = __hip_atomic_fetch_add(ctr, 1u, __ATOMIC_RELAXED,
                                            __HIP_MEMORY_SCOPE_AGENT);
        unsigned target = (t & ~15u) + 16u;
        while (__hip_atomic_load(ctr, __ATOMIC_RELAXED,
                                 __HIP_MEMORY_SCOPE_AGENT) < target)
            __builtin_amdgcn_s_sleep(1);
    }
    __syncthreads();
}

// ---------------- K0: casts + packing + a0 (unchanged, validated) ----------------
__global__ __launch_bounds__(256) void k0_prep(
    const float* __restrict__ z, const float* __restrict__ x,
    const float* __restrict__ x0, const float* __restrict__ W_ia,
    const float* __restrict__ b_ia, const float* __restrict__ W_ih,
    const float* __restrict__ W_hh, const float* __restrict__ W_h0,
    const float* __restrict__ W_out, const float* __restrict__ b_hh,
    _Float16* __restrict__ zx16, _Float16* __restrict__ wcat16,
    _Float16* __restrict__ whh16, float* __restrict__ pk, float* __restrict__ xbuf)
{
    const int ZX = 4096 * 256, WC = 2048 * 256, WH = 1536 * 512, PKN = 512, XB = 4096 * 2;
    const int total = ZX + WC + WH + PKN + XB;
    for (int idx = blockIdx.x * 256 + threadIdx.x; idx < total; idx += gridDim.x * 256) {
        if (idx < ZX) {
            int i = idx >> 8, k = idx & 255;
            float v = (k < 128) ? z[i * 128 + k] : x[i * 128 + (k - 128)];
            zx16[idx] = (_Float16)v;
        } else if (idx < ZX + WC) {
            int j = idx - ZX;
            int n = j >> 8, k = j & 255;
            float v = (n < 512) ? W_h0[n * 256 + k] : W_ih[(n - 512) * 258 + k];
            wcat16[j] = (_Float16)v;
        } else if (idx < ZX + WC + WH) {
            int j = idx - ZX - WC;
            whh16[j] = (_Float16)W_hh[j];
        } else if (idx < ZX + WC + WH + PKN) {
            int jc = idx - ZX - WC - WH;
            float* o = pk + jc * 12;
            o[0] = W_ih[jc * 258 + 256];          o[1] = W_ih[jc * 258 + 257];
            o[2] = W_ih[(512 + jc) * 258 + 256];  o[3] = W_ih[(512 + jc) * 258 + 257];
            o[4] = W_ih[(1024 + jc) * 258 + 256]; o[5] = W_ih[(1024 + jc) * 258 + 257];
            o[6] = b_hh[jc]; o[7] = b_hh[512 + jc]; o[8] = b_hh[1024 + jc];
            o[9] = W_out[jc]; o[10] = W_out[512 + jc]; o[11] = 0.f;
        } else {
            int j = idx - ZX - WC - WH - PKN;
            int i = j >> 1, d = j & 1;
            float s = b_ia[d];
            #pragma unroll
            for (int k2 = 0; k2 < 4; k2++) s += x0[i * 4 + k2] * W_ia[d * 4 + k2];
            xbuf[j] = s;
        }
    }
}

// ---------------- K2: fused pre-GEMM + XCD-local persistent 12-step GRU ----------------
// LDS: B region @0 (96KB: pre-phase uses 128 rows x 512B = 64KB, steps use
// 96 rows x 1024B), hstore[256][32]h @98304, xs @114688, oac @116736, slot @118784.
__global__ __launch_bounds__(512, 1) void k2_fused(
    const _Float16* __restrict__ zx16, const _Float16* __restrict__ wcat16,
    const _Float16* __restrict__ whh16, const float* __restrict__ pk,
    const float* __restrict__ xbuf, const float* __restrict__ b_h0,
    const float* __restrict__ b_ih, float* __restrict__ dout,
    const float* __restrict__ b_out)
{
    extern __shared__ __align__(16) char smem[];
    const uint32_t BOFF = 0, HST = 98304, XSO = 114688, OAC = 116736, SLO = 118784;
    const int tid = threadIdx.x;
    float* xs  = (float*)(smem + XSO);
    float* oacf = (float*)(smem + OAC);

    // ---- XCD discovery + registration (validated R11) ----
    unsigned xcc;
    asm volatile("s_getreg_b32 %0, hwreg(HW_REG_XCC_ID)" : "=s"(xcc));
    xcc &= 7u;
    if (tid == 0) {
        unsigned s = __hip_atomic_fetch_add(&g_cnt[xcc * 64], 1u, __ATOMIC_RELAXED,
                                            __HIP_MEMORY_SCOPE_AGENT) & 31u;
        *(unsigned*)(smem + SLO) = s;
    }
    __syncthreads();
    const unsigned slot = *(volatile unsigned*)(smem + SLO);
    const int shalf = slot >> 4, cgrp = slot & 15;
    const unsigned gidx = xcc * 2 + shalf;      // 0..15, 16 blocks each
    const int M0 = (int)gidx * 256;             // group's 256 samples
    const int jc0 = cgrp * 32;                  // block's 32 h-cols (x3 gates)

    const int wv = tid >> 6, lane = tid & 63;
    const int l15 = lane & 15, q2 = lane >> 4;

    // ---- stage pre-B: 128 rows x 256 fp16 (512B) from wcat16, swizzled ----
    // rows 0..95: W_ih gate rows (r = g*32+jin -> wcat row 512+g*512+jc0+jin)
    // rows 96..127: W_h0 rows (wcat row jc0 + (r-96)). Two rows per async16.
    {
        #pragma unroll
        for (int j2 = 0; j2 < 8; j2++) {
            int p = j2 * 8 + wv;              // 0..63 (wave-uniform)
            int r0 = p * 2;
            int r = r0 + (lane >> 5);
            int s = lane & 31;
            int n = (r < 96) ? (512 + (r >> 5) * 512 + jc0 + (r & 31))
                             : (jc0 + (r - 96));
            const _Float16* src = wcat16 + (size_t)n * 256 + ((s ^ (r & 15)) << 3);
            async16(smem + (uint32_t)r0 * 512, src);
        }
    }

    // ---- t-invariant params ----
    float4 p0v[2], p1v[2], p2v[2]; float wo0[2], wo1[2];
    float bih[3][2], bh0[2];
    #pragma unroll
    for (int jt = 0; jt < 2; jt++) {
        int jc = jc0 + jt * 16 + l15;
        const float4* pkp = (const float4*)(pk + (size_t)jc * 12);
        p0v[jt] = pkp[0]; p1v[jt] = pkp[1]; p2v[jt] = pkp[2];
        wo0[jt] = p2v[jt].y; wo1[jt] = p2v[jt].z;
        bh0[jt] = b_h0[jc];
        #pragma unroll
        for (int g = 0; g < 3; g++) bih[g][jt] = b_ih[g * 512 + jc];
    }
    // step-GEMM A offsets (1024B rows), step-B read bases (validated R11)
    size_t aoff0 = ((size_t)(M0 + (wv * 2 + 0) * 16 + l15) * 512) * 2 + (size_t)q2 * 16;
    size_t aoff1 = ((size_t)(M0 + (wv * 2 + 1) * 16 + l15) * 512) * 2 + (size_t)q2 * 16;
    uint32_t bbase[6];
    #pragma unroll
    for (int g = 0; g < 3; g++)
        #pragma unroll
        for (int jt = 0; jt < 2; jt++) {
            int r = g * 32 + jt * 16 + l15;
            bbase[g * 2 + jt] = BOFF + (uint32_t)r * 1024 +
                                ((uint32_t)(q2 ^ (r & 3)) << 4) +
                                ((uint32_t)((r >> 2) & 3) << 6);
        }
    // pre-GEMM B read bases (512B rows): slots 0..5 gi (g*2+jt), 6..7 h0 (jt)
    uint32_t pb[8];
    #pragma unroll
    for (int sl = 0; sl < 8; sl++) {
        int r = (sl < 6) ? ((sl >> 1) * 32 + (sl & 1) * 16 + l15)
                         : (96 + (sl - 6) * 16 + l15);
        pb[sl] = BOFF + (uint32_t)r * 512 +
                 ((uint32_t)(q2 ^ (r & 3)) << 4) +
                 ((uint32_t)((r >> 2) & 3) << 6);
    }
    __syncthreads();   // pre-B staged (sync drains vmcnt; validated pattern)

    // ---- pre-GEMM: K=256, A=zx16 (512B rows), 8 ks, depth-3 queue ----
    size_t zoff0 = ((size_t)(M0 + (wv * 2 + 0) * 16 + l15) * 256) * 2 + (size_t)q2 * 16;
    size_t zoff1 = ((size_t)(M0 + (wv * 2 + 1) * 16 + l15) * 256) * 2 + (size_t)q2 * 16;
    const char* zp0 = (const char*)zx16 + zoff0;
    const char* zp1 = (const char*)zx16 + zoff1;
    floatx4 accP[2][8];
    #pragma unroll
    for (int mt = 0; mt < 2; mt++)
        #pragma unroll
        for (int sl = 0; sl < 8; sl++) accP[mt][sl] = (floatx4){0.f, 0.f, 0.f, 0.f};
    {
        f16x8 aq[4][2];
        #define ALOADZ(S, KS) do { \
            aq[S][0] = *(const f16x8*)(zp0 + (KS) * 64); \
            aq[S][1] = *(const f16x8*)(zp1 + (KS) * 64); \
        } while (0)
        ALOADZ(0, 0); ALOADZ(1, 1); ALOADZ(2, 2);
        #pragma unroll
        for (int ks = 0; ks < 8; ks++) {
            if (ks < 5) { ALOADZ((ks + 3) & 3, ks + 3); }
            f16x8 a0 = aq[ks & 3][0];
            f16x8 a1 = aq[ks & 3][1];
            const uint32_t kadd = (uint32_t)((ks >> 2) << 8);
            const uint32_t kxor = (uint32_t)((ks & 3) << 6);
            #pragma unroll
            for (int sl = 0; sl < 8; sl++) {
                f16x8 b = *(const f16x8*)(smem + ((pb[sl] + kadd) ^ kxor));
                accP[0][sl] = __builtin_amdgcn_mfma_f32_16x16x32_f16(a0, b, accP[0][sl], 0, 0, 0);
                accP[1][sl] = __builtin_amdgcn_mfma_f32_16x16x32_f16(a1, b, accP[1][sl], 0, 0, 0);
            }
        }
        #undef ALOADZ
    }

    // ---- gi -> registers (+bias); h0 -> hstore ----
    float gi[2][3][2][4];
    #pragma unroll
    for (int mt = 0; mt < 2; mt++)
        #pragma unroll
        for (int g = 0; g < 3; g++)
            #pragma unroll
            for (int jt = 0; jt < 2; jt++)
                #pragma unroll
                for (int reg = 0; reg < 4; reg++)
                    gi[mt][g][jt][reg] = accP[mt][g * 2 + jt][reg] + bih[g][jt];
    #pragma unroll
    for (int mt = 0; mt < 2; mt++)
        #pragma unroll
        for (int jt = 0; jt < 2; jt++)
            #pragma unroll
            for (int reg = 0; reg < 4; reg++) {
                int rl = (wv * 2 + mt) * 16 + q2 * 4 + reg;
                float v = accP[mt][6 + jt][reg] + bh0[jt];
                *(_Float16*)(smem + HST + (uint32_t)(rl * 32 + jt * 16 + l15) * 2) = (_Float16)v;
            }
    __syncthreads();   // all pre-B reads + hstore writes complete

    // ---- stage W_hh (96 rows x 512, 96KB) -- overlaps publish + barrier ----
    {
        #pragma unroll
        for (int j = 0; j < 12; j++) {
            int r = j * 8 + wv;               // 0..95
            int n = (r >> 5) * 512 + jc0 + (r & 31);
            const _Float16* src = whh16 + (size_t)n * 512 + ((lane ^ (r & 15)) << 3);
            async16(smem + BOFF + (uint32_t)r * 1024, src);
        }
    }
    // ---- publish h0 slice ----
    {
        int row = tid >> 1, ch = (tid & 1) * 16;
        const unsigned long long* sl =
            (const unsigned long long*)(smem + HST + (uint32_t)(row * 32 + ch) * 2);
        unsigned long long* gd =
            (unsigned long long*)(&g_h[0][0] + (size_t)(M0 + row) * 512 + jc0 + ch);
        gd[0] = sl[0]; gd[1] = sl[1]; gd[2] = sl[2]; gd[3] = sl[3];
    }
    group_barrier16(gidx);   // drains whh staging + h0 publish

    // ---- 12-step loop ----
    #pragma unroll 1
    for (int t = 0; t < 12; t++) {
        const _Float16* hcur = &g_h[t][0];

        // ---- GEMM first: K=512, A from L2-local g_h[t], depth-3 queue ----
        const char* rp0 = (const char*)hcur + aoff0;
        const char* rp1 = (const char*)hcur + aoff1;
        floatx4 acc[2][3][2];
        #pragma unroll
        for (int mt = 0; mt < 2; mt++)
            #pragma unroll
            for (int g = 0; g < 3; g++)
                #pragma unroll
                for (int jt = 0; jt < 2; jt++)
                    acc[mt][g][jt] = (floatx4){0.f, 0.f, 0.f, 0.f};

        f16x8 aq[4][2];
        #define ALOAD(S, KS) do { \
            aq[S][0] = *(const f16x8*)(rp0 + (KS) * 64); \
            aq[S][1] = *(const f16x8*)(rp1 + (KS) * 64); \
        } while (0)
        ALOAD(0, 0); ALOAD(1, 1); ALOAD(2, 2);
        #pragma unroll
        for (int ks = 0; ks < 16; ks++) {
            if (ks < 13) { ALOAD((ks + 3) & 3, ks + 3); }
            f16x8 a0 = aq[ks & 3][0];
            f16x8 a1 = aq[ks & 3][1];
            const uint32_t kadd = (uint32_t)((ks >> 2) << 8);
            const uint32_t kxor = (uint32_t)((ks & 3) << 6);
            #pragma unroll
            for (int g = 0; g < 3; g++)
                #pragma unroll
                for (int jt = 0; jt < 2; jt++) {
                    f16x8 b = *(const f16x8*)(smem + ((bbase[g * 2 + jt] + kadd) ^ kxor));
                    acc[0][g][jt] = __builtin_amdgcn_mfma_f32_16x16x32_f16(a0, b, acc[0][g][jt], 0, 0, 0);
                    acc[1][g][jt] = __builtin_amdgcn_mfma_f32_16x16x32_f16(a1, b, acc[1][g][jt], 0, 0, 0);
                }
        }
        #undef ALOAD

        // ---- prologue AFTER GEMM: x_t (+ dout_{t-1}); latency hidden ----
        {
            int i = tid >> 1, d = tid & 1;
            float v;
            if (t == 0) {
                v = xbuf[(size_t)(M0 + i) * 2 + d];
            } else {
                const float4* p = (const float4*)(&g_P[t - 1][0] + ((size_t)(M0 + i) * 2 + d) * 16);
                float4 a = p[0], b = p[1], c = p[2], e = p[3];
                v = b_out[d] + a.x + a.y + a.z + a.w + b.x + b.y + b.z + b.w
                             + c.x + c.y + c.z + c.w + e.x + e.y + e.z + e.w;
                if (cgrp == 0) dout[((size_t)(M0 + i) * 12 + (t - 1)) * 2 + d] = v;
            }
            xs[tid] = v;
        }
        __syncthreads();

        // ---- epilogue: gates (gi from REGISTERS), hn -> hstore, out-partials ----
        float po[2][4][2];
        #pragma unroll
        for (int mt = 0; mt < 2; mt++)
            #pragma unroll
            for (int reg = 0; reg < 4; reg++) { po[mt][reg][0] = 0.f; po[mt][reg][1] = 0.f; }

        #pragma unroll
        for (int mt = 0; mt < 2; mt++) {
            #pragma unroll
            for (int jt = 0; jt < 2; jt++) {
                #pragma unroll
                for (int reg = 0; reg < 4; reg++) {
                    int rl = (wv * 2 + mt) * 16 + q2 * 4 + reg;   // local row 0..255
                    float x0v = xs[rl * 2], x1v = xs[rl * 2 + 1];
                    _Float16* hp = (_Float16*)(smem + HST + (uint32_t)(rl * 32 + jt * 16 + l15) * 2);
                    float hold = (float)hp[0];
                    float r  = sigm_f(gi[mt][0][jt][reg] + p0v[jt].x * x0v + p0v[jt].y * x1v + acc[mt][0][jt][reg] + p1v[jt].z);
                    float u  = sigm_f(gi[mt][1][jt][reg] + p0v[jt].z * x0v + p0v[jt].w * x1v + acc[mt][1][jt][reg] + p1v[jt].w);
                    float nn = tanh_f(gi[mt][2][jt][reg] + p1v[jt].x * x0v + p1v[jt].y * x1v + r * (acc[mt][2][jt][reg] + p2v[jt].x));
                    float hn = (1.f - u) * nn + u * hold;
                    hp[0] = (_Float16)hn;
                    po[mt][reg][0] += hn * wo0[jt];
                    po[mt][reg][1] += hn * wo1[jt];
                }
            }
        }
        #pragma unroll
        for (int m = 1; m < 16; m <<= 1)
            #pragma unroll
            for (int mt = 0; mt < 2; mt++)
                #pragma unroll
                for (int reg = 0; reg < 4; reg++) {
                    po[mt][reg][0] += __shfl_xor(po[mt][reg][0], m);
                    po[mt][reg][1] += __shfl_xor(po[mt][reg][1], m);
                }
        if (l15 == 0) {
            #pragma unroll
            for (int mt = 0; mt < 2; mt++)
                #pragma unroll
                for (int reg = 0; reg < 4; reg++) {
                    int rl = (wv * 2 + mt) * 16 + q2 * 4 + reg;
                    ((float2*)oacf)[rl] = make_float2(po[mt][reg][0], po[mt][reg][1]);
                }
        }
        __syncthreads();   // hstore + oacf complete across waves

        // ---- publish h slice (t<11 -> g_h[t+1]) + partials: plain L2 stores ----
        if (t < 11) {
            int row = tid >> 1, ch = (tid & 1) * 16;
            const unsigned long long* sl =
                (const unsigned long long*)(smem + HST + (uint32_t)(row * 32 + ch) * 2);
            unsigned long long* gd =
                (unsigned long long*)(&g_h[t + 1][0] + (size_t)(M0 + row) * 512 + jc0 + ch);
            gd[0] = sl[0]; gd[1] = sl[1]; gd[2] = sl[2]; gd[3] = sl[3];
        }
        g_P[t][((size_t)(M0 + (tid >> 1)) * 2 + (tid & 1)) * 16 + cgrp] = oacf[tid];
        group_barrier16(gidx);
    }

    // ---- final output out_11 ----
    if (cgrp == 0) {
        int i = M0 + (tid >> 1), d = tid & 1;
        const float4* p = (const float4*)(&g_P[11][0] + ((size_t)i * 2 + d) * 16);
        float4 a = p[0], b = p[1], c = p[2], e = p[3];
        float v = b_out[d] + a.x + a.y + a.z + a.w + b.x + b.y + b.z + b.w
                           + c.x + c.y + c.z + c.w + e.x + e.y + e.z + e.w;
        dout[((size_t)i * 12 + 11) * 2 + d] = v;
    }
}

extern "C" void kernel_launch(void* const* d_in, const int* in_sizes, int n_in,
                              void* d_out, int out_size, void* d_ws, size_t ws_size,
                              hipStream_t stream)
{
    const float* z     = (const float*)d_in[0];
    const float* x     = (const float*)d_in[1];
    const float* x0    = (const float*)d_in[2];
    const float* W_ia  = (const float*)d_in[3];
    const float* b_ia  = (const float*)d_in[4];
    const float* W_h0  = (const float*)d_in[5];
    const float* b_h0  = (const float*)d_in[6];
    const float* W_ih  = (const float*)d_in[7];
    const float* b_ih  = (const float*)d_in[8];
    const float* W_hh  = (const float*)d_in[9];
    const float* b_hh  = (const float*)d_in[10];
    const float* W_out = (const float*)d_in[11];
    const float* b_out = (const float*)d_in[12];
    float* dout = (float*)d_out;

    char* ws = (char*)d_ws;
    _Float16* zx16   = (_Float16*)(ws + 20971520);   // 2 MiB
    _Float16* wcat16 = (_Float16*)(ws + 23068672);   // 1 MiB
    _Float16* whh16  = (_Float16*)(ws + 24117248);   // 1.5 MiB
    float*    pk     = (float*)(ws + 25690112);      // 24 KiB
    float*    xbuf   = (float*)(ws + 25714688);      // 32 KiB

    static bool s_attr_done = false;
    if (!s_attr_done) {
        hipFuncSetAttribute((const void*)k2_fused,
                            hipFuncAttributeMaxDynamicSharedMemorySize, 118848);
        s_attr_done = true;
    }

    k0_prep<<<2048, 256, 0, stream>>>(z, x, x0, W_ia, b_ia, W_ih, W_hh, W_h0,
                                      W_out, b_hh, zx16, wcat16, whh16, pk, xbuf);
    k2_fused<<<256, 512, 118848, stream>>>(zx16, wcat16, whh16, pk, xbuf,
                                           b_h0, b_ih, dout, b_out);
}